// Round 3
// baseline (983.035 us; speedup 1.0000x reference)
//
#include <hip/hip_runtime.h>

#define HH 128
#define GG 32
#define LL 3
#define BN_EPS 1e-5f

// ---- CSR build ----
__global__ __launch_bounds__(256) void k_deg(const int* __restrict__ ei, int* __restrict__ deg, int E) {
  int e = blockIdx.x * 256 + threadIdx.x;
  if (e < E) atomicAdd(&deg[ei[E + e]], 1);
}

__global__ __launch_bounds__(256) void k_gcnt(const int* __restrict__ batch, int* __restrict__ gcnt, int N) {
  int n = blockIdx.x * 256 + threadIdx.x;
  if (n < N) atomicAdd(&gcnt[batch[n]], 1);
}

// ---- parallel 3-phase exclusive scan ----
__global__ __launch_bounds__(1024) void k_scan_blk(const int* __restrict__ in, int* __restrict__ out,
                                                   int* __restrict__ bsum, int n) {
  __shared__ int sd[1024];
  int tid = threadIdx.x;
  int i = blockIdx.x * 1024 + tid;
  int v = (i < n) ? in[i] : 0;
  sd[tid] = v;
  __syncthreads();
  for (int off = 1; off < 1024; off <<= 1) {
    int t = (tid >= off) ? sd[tid - off] : 0;
    __syncthreads();
    sd[tid] += t;
    __syncthreads();
  }
  if (i < n) out[i] = sd[tid] - v;
  if (tid == 1023) bsum[blockIdx.x] = sd[1023];
}

__global__ __launch_bounds__(1024) void k_scan_top(int* __restrict__ bsum, int nb) {
  __shared__ int sd[1024];
  int tid = threadIdx.x;
  int v = (tid < nb) ? bsum[tid] : 0;
  sd[tid] = v;
  __syncthreads();
  for (int off = 1; off < 1024; off <<= 1) {
    int t = (tid >= off) ? sd[tid - off] : 0;
    __syncthreads();
    sd[tid] += t;
    __syncthreads();
  }
  if (tid < nb) bsum[tid] = sd[tid] - v;
}

__global__ __launch_bounds__(1024) void k_scan_add(int* __restrict__ out0, int* __restrict__ out1,
                                                   const int* __restrict__ bsum, int n) {
  int i = blockIdx.x * 1024 + threadIdx.x;
  if (i < n) {
    int v = out0[i] + bsum[blockIdx.x];
    out0[i] = v;
    if (out1) out1[i] = v;
  }
}

__global__ __launch_bounds__(256) void k_scatter(const int* __restrict__ ei, int* __restrict__ cursor,
                                                 int* __restrict__ csr_src, int E) {
  int e = blockIdx.x * 256 + threadIdx.x;
  if (e < E) {
    int d = ei[E + e];
    int p = atomicAdd(&cursor[d], 1);
    csr_src[p] = ei[e];
  }
}

// ---- fused: mean-aggregate (gather) + dual GEMM + bias + BN + ReLU, 64 rows/block ----
__global__ __launch_bounds__(256) void k_fused(const int* __restrict__ csr_off, const int* __restrict__ deg,
                                               const int* __restrict__ csr_src, const float* __restrict__ hin,
                                               const float* __restrict__ wlp, const float* __restrict__ wrp,
                                               const float* __restrict__ bias, const float* __restrict__ gma,
                                               const float* __restrict__ bta, const float* __restrict__ mea,
                                               const float* __restrict__ var, float* __restrict__ hout, int N) {
  __shared__ float AgT[HH][68];  // transposed agg tile [k][row], 34816 B
  __shared__ float As[32][68];   // hin staging [k][row], 8704 B
  __shared__ float Ws[32][HH];   // weight chunk [k][col], 16384 B
  int tid = threadIdx.x;
  int n0 = blockIdx.x * 64;
  int w = tid >> 6;
  int lane = tid & 63;
  int half = lane >> 5;
  int colq = (lane & 31) * 4;

  // Phase A: gather-mean 16 nodes per wave into AgT (transposed)
  for (int i = 0; i < 16; i++) {
    int row = w * 16 + i;
    int node = n0 + row;
    float ax = 0.f, ay = 0.f, az = 0.f, aw = 0.f;
    float inv = 0.f;
    if (node < N) {
      int off = csr_off[node];
      int d = deg[node];
      int j = 0;
      for (; j + 4 <= d; j += 4) {
        int sA = csr_src[off + j + half];
        int sB = csr_src[off + j + 2 + half];
        float4 vA = *(const float4*)&hin[(size_t)sA * HH + colq];
        float4 vB = *(const float4*)&hin[(size_t)sB * HH + colq];
        ax += vA.x; ay += vA.y; az += vA.z; aw += vA.w;
        ax += vB.x; ay += vB.y; az += vB.z; aw += vB.w;
      }
      for (; j + 2 <= d; j += 2) {
        int s = csr_src[off + j + half];
        float4 v = *(const float4*)&hin[(size_t)s * HH + colq];
        ax += v.x; ay += v.y; az += v.z; aw += v.w;
      }
      if (j < d && half == 0) {
        int s = csr_src[off + j];
        float4 v = *(const float4*)&hin[(size_t)s * HH + colq];
        ax += v.x; ay += v.y; az += v.z; aw += v.w;
      }
      inv = d > 0 ? 1.0f / (float)d : 0.0f;
    }
    ax += __shfl_down(ax, 32);
    ay += __shfl_down(ay, 32);
    az += __shfl_down(az, 32);
    aw += __shfl_down(aw, 32);
    if (half == 0) {
      AgT[colq + 0][row] = ax * inv;
      AgT[colq + 1][row] = ay * inv;
      AgT[colq + 2][row] = az * inv;
      AgT[colq + 3][row] = aw * inv;
    }
  }

  // Phase B: dual GEMM. acc = AgT(64x128) @ wl + hin(64x128) @ wr
  int tc = tid & 31, tr = tid >> 5;
  int c0 = tc * 4, r0 = tr * 8;
  float acc[8][4] = {};

  // Pass 1: agg @ wl, A-fragments straight from AgT
  for (int k0 = 0; k0 < HH; k0 += 32) {
    {
      const float4* srcp = (const float4*)(wlp + (size_t)k0 * HH);
      float4* dstp = (float4*)&Ws[0][0];
#pragma unroll
      for (int jj = 0; jj < 4; jj++) dstp[tid + jj * 256] = srcp[tid + jj * 256];
    }
    __syncthreads();  // also orders Phase A writes before reads
#pragma unroll
    for (int k = 0; k < 32; k++) {
      float a0[8], w0[4];
      *(float4*)&a0[0] = *(const float4*)&AgT[k0 + k][r0];
      *(float4*)&a0[4] = *(const float4*)&AgT[k0 + k][r0 + 4];
      *(float4*)&w0[0] = *(const float4*)&Ws[k][c0];
#pragma unroll
      for (int r = 0; r < 8; r++)
#pragma unroll
        for (int c = 0; c < 4; c++) acc[r][c] = fmaf(a0[r], w0[c], acc[r][c]);
    }
    __syncthreads();
  }

  // Pass 2: hin @ wr, A staged from global per k-chunk
  for (int k0 = 0; k0 < HH; k0 += 32) {
    {
      int row = tid >> 2;
      int kq = (tid & 3) * 8;
      int n = n0 + row;
      float4 v0, v1;
      if (n < N) {
        const float* p = hin + (size_t)n * HH + k0 + kq;
        v0 = *(const float4*)p;
        v1 = *(const float4*)(p + 4);
      } else {
        v0 = make_float4(0.f, 0.f, 0.f, 0.f);
        v1 = v0;
      }
      As[kq + 0][row] = v0.x; As[kq + 1][row] = v0.y;
      As[kq + 2][row] = v0.z; As[kq + 3][row] = v0.w;
      As[kq + 4][row] = v1.x; As[kq + 5][row] = v1.y;
      As[kq + 6][row] = v1.z; As[kq + 7][row] = v1.w;
    }
    {
      const float4* srcp = (const float4*)(wrp + (size_t)k0 * HH);
      float4* dstp = (float4*)&Ws[0][0];
#pragma unroll
      for (int jj = 0; jj < 4; jj++) dstp[tid + jj * 256] = srcp[tid + jj * 256];
    }
    __syncthreads();
#pragma unroll
    for (int k = 0; k < 32; k++) {
      float a0[8], w0[4];
      *(float4*)&a0[0] = *(const float4*)&As[k][r0];
      *(float4*)&a0[4] = *(const float4*)&As[k][r0 + 4];
      *(float4*)&w0[0] = *(const float4*)&Ws[k][c0];
#pragma unroll
      for (int r = 0; r < 8; r++)
#pragma unroll
        for (int c = 0; c < 4; c++) acc[r][c] = fmaf(a0[r], w0[c], acc[r][c]);
    }
    __syncthreads();
  }

  // epilogue: bias + BN + ReLU folded
  float sc[4], sh[4];
#pragma unroll
  for (int c = 0; c < 4; c++) {
    float g = gma[c0 + c], vv = var[c0 + c], m = mea[c0 + c], bt = bta[c0 + c], bb = bias[c0 + c];
    float s = g * rsqrtf(vv + BN_EPS);
    sc[c] = s;
    sh[c] = (bb - m) * s + bt;
  }
#pragma unroll
  for (int r = 0; r < 8; r++) {
    int n = n0 + r0 + r;
    if (n < N) {
      float4 o;
      o.x = fmaxf(acc[r][0] * sc[0] + sh[0], 0.f);
      o.y = fmaxf(acc[r][1] * sc[1] + sh[1], 0.f);
      o.z = fmaxf(acc[r][2] * sc[2] + sh[2], 0.f);
      o.w = fmaxf(acc[r][3] * sc[3] + sh[3], 0.f);
      *(float4*)&hout[(size_t)n * HH + c0] = o;
    }
  }
}

// ---- graph pooling + concat global feats ----
__global__ __launch_bounds__(128) void k_pool(const float* __restrict__ h, const int* __restrict__ goff,
                                              const int* __restrict__ gcnt, const float* __restrict__ gfeat,
                                              float* __restrict__ pz) {
  int g = blockIdx.x;
  int t = threadIdx.x;
  int off = goff[g], cnt = gcnt[g];
  float s = 0.f;
  for (int j = 0; j < cnt; j++) s += h[(size_t)(off + j) * HH + t];
  float inv = cnt > 0 ? 1.0f / (float)cnt : 0.f;
  pz[(size_t)g * (HH + GG) + t] = s * inv;
  if (t < GG) pz[(size_t)g * (HH + GG) + HH + t] = gfeat[g * GG + t];
}

// ---- final MLP: one wave per graph ----
__global__ __launch_bounds__(64) void k_mlp(const float* __restrict__ pz, const float* __restrict__ w1,
                                            const float* __restrict__ b1, const float* __restrict__ w2,
                                            const float* __restrict__ b2, float* __restrict__ out) {
  int g = blockIdx.x;
  int t = threadIdx.x;
  const float* z = pz + (size_t)g * (HH + GG);
  float acc = b1[t];
  for (int k = 0; k < HH + GG; k++) acc = fmaf(z[k], w1[k * 64 + t], acc);
  acc = fmaxf(acc, 0.f);
  float v = acc * w2[t];
#pragma unroll
  for (int o = 32; o > 0; o >>= 1) v += __shfl_down(v, o);
  if (t == 0) out[g] = v + b2[0];
}

extern "C" void kernel_launch(void* const* d_in, const int* in_sizes, int n_in,
                              void* d_out, int out_size, void* d_ws, size_t ws_size,
                              hipStream_t stream) {
  const float* x = (const float*)d_in[0];
  const int* ei = (const int*)d_in[1];
  const int* batch = (const int*)d_in[2];
  const float* gfeat = (const float*)d_in[3];
  const float* wl = (const float*)d_in[4];
  const float* wr = (const float*)d_in[5];
  const float* bias = (const float*)d_in[6];
  const float* gma = (const float*)d_in[7];
  const float* bta = (const float*)d_in[8];
  const float* mea = (const float*)d_in[9];
  const float* var = (const float*)d_in[10];
  const float* w1 = (const float*)d_in[11];
  const float* b1 = (const float*)d_in[12];
  const float* w2 = (const float*)d_in[13];
  const float* b2 = (const float*)d_in[14];
  int N = in_sizes[0] / HH;
  int E = in_sizes[1] / 2;
  int B = in_sizes[3] / GG;
  float* out = (float*)d_out;
  (void)n_in; (void)out_size; (void)ws_size;

  char* base = (char*)d_ws;
  size_t off = 0;
  auto alloc = [&](size_t bytes) -> void* {
    void* p = base + off;
    off = (off + bytes + 255) & ~(size_t)255;
    return p;
  };
  int* deg = (int*)alloc((size_t)N * 4);
  int* csr_off = (int*)alloc((size_t)N * 4);
  int* cursor = (int*)alloc((size_t)N * 4);
  int* gcnt = (int*)alloc((size_t)B * 4);
  int* goff = (int*)alloc((size_t)B * 4);
  int* csr_src = (int*)alloc((size_t)E * 4);
  float* hbA = (float*)alloc((size_t)N * HH * 4);
  float* hbB = (float*)alloc((size_t)N * HH * 4);
  float* pz = (float*)alloc((size_t)B * (HH + GG) * 4);
  int* bsumN = (int*)alloc(1024 * 4);
  int* bsumB = (int*)alloc(1024 * 4);

  hipMemsetAsync(deg, 0, (size_t)N * 4, stream);
  hipMemsetAsync(gcnt, 0, (size_t)B * 4, stream);
  k_deg<<<(E + 255) / 256, 256, 0, stream>>>(ei, deg, E);
  k_gcnt<<<(N + 255) / 256, 256, 0, stream>>>(batch, gcnt, N);

  int nbN = (N + 1023) / 1024;
  k_scan_blk<<<nbN, 1024, 0, stream>>>(deg, csr_off, bsumN, N);
  k_scan_top<<<1, 1024, 0, stream>>>(bsumN, nbN);
  k_scan_add<<<nbN, 1024, 0, stream>>>(csr_off, cursor, bsumN, N);

  int nbB = (B + 1023) / 1024;
  k_scan_blk<<<nbB, 1024, 0, stream>>>(gcnt, goff, bsumB, B);
  k_scan_top<<<1, 1024, 0, stream>>>(bsumB, nbB);
  k_scan_add<<<nbB, 1024, 0, stream>>>(goff, (int*)nullptr, bsumB, B);

  k_scatter<<<(E + 255) / 256, 256, 0, stream>>>(ei, cursor, csr_src, E);

  int nblk = (N + 63) / 64;
  const float* hsrc[LL] = {x, hbA, hbB};
  float* hdst[LL] = {hbA, hbB, hbA};
  for (int l = 0; l < LL; l++) {
    k_fused<<<nblk, 256, 0, stream>>>(csr_off, deg, csr_src, hsrc[l],
                                      wl + (size_t)l * HH * HH, wr + (size_t)l * HH * HH,
                                      bias + (size_t)l * HH, gma + (size_t)l * HH, bta + (size_t)l * HH,
                                      mea + (size_t)l * HH, var + (size_t)l * HH, hdst[l], N);
  }
  k_pool<<<B, 128, 0, stream>>>(hbA, goff, gcnt, gfeat, pz);
  k_mlp<<<B, 64, 0, stream>>>(pz, w1, b1, w2, b2, out);
}

// Round 4
// 436.465 us; speedup vs baseline: 2.2523x; 2.2523x over previous
//
#include <hip/hip_runtime.h>

#define HH 128
#define GG 32
#define LL 3
#define BN_EPS 1e-5f

typedef unsigned short ushortT;
typedef unsigned int uintT;

__device__ inline ushortT f2bf(float f) {
  uintT u = __float_as_uint(f);
  u += 0x7fff + ((u >> 16) & 1);  // RNE
  return (ushortT)(u >> 16);
}
__device__ inline float bf2f(ushortT u) { return __uint_as_float(((uintT)u) << 16); }

// ---- CSR build ----
__global__ __launch_bounds__(256) void k_deg(const int* __restrict__ ei, int* __restrict__ deg, int E) {
  int e = blockIdx.x * 256 + threadIdx.x;
  if (e < E) atomicAdd(&deg[ei[E + e]], 1);
}

__global__ __launch_bounds__(256) void k_gcnt(const int* __restrict__ batch, int* __restrict__ gcnt, int N) {
  int n = blockIdx.x * 256 + threadIdx.x;
  if (n < N) atomicAdd(&gcnt[batch[n]], 1);
}

// ---- parallel 3-phase exclusive scan ----
__global__ __launch_bounds__(1024) void k_scan_blk(const int* __restrict__ in, int* __restrict__ out,
                                                   int* __restrict__ bsum, int n) {
  __shared__ int sd[1024];
  int tid = threadIdx.x;
  int i = blockIdx.x * 1024 + tid;
  int v = (i < n) ? in[i] : 0;
  sd[tid] = v;
  __syncthreads();
  for (int off = 1; off < 1024; off <<= 1) {
    int t = (tid >= off) ? sd[tid - off] : 0;
    __syncthreads();
    sd[tid] += t;
    __syncthreads();
  }
  if (i < n) out[i] = sd[tid] - v;
  if (tid == 1023) bsum[blockIdx.x] = sd[1023];
}

__global__ __launch_bounds__(1024) void k_scan_top(int* __restrict__ bsum, int nb) {
  __shared__ int sd[1024];
  int tid = threadIdx.x;
  int v = (tid < nb) ? bsum[tid] : 0;
  sd[tid] = v;
  __syncthreads();
  for (int off = 1; off < 1024; off <<= 1) {
    int t = (tid >= off) ? sd[tid - off] : 0;
    __syncthreads();
    sd[tid] += t;
    __syncthreads();
  }
  if (tid < nb) bsum[tid] = sd[tid] - v;
}

__global__ __launch_bounds__(1024) void k_scan_add(int* __restrict__ out0, int* __restrict__ out1,
                                                   const int* __restrict__ bsum, int n) {
  int i = blockIdx.x * 1024 + threadIdx.x;
  if (i < n) {
    int v = out0[i] + bsum[blockIdx.x];
    out0[i] = v;
    if (out1) out1[i] = v;
  }
}

// ---- windowed scatter: only edges whose dst falls in [lo,hi) ----
__global__ __launch_bounds__(256) void k_scatter(const int* __restrict__ ei, int* __restrict__ cursor,
                                                 int* __restrict__ csr_src, int E, int lo, int hi) {
  int e = blockIdx.x * 256 + threadIdx.x;
  if (e < E) {
    int d = ei[E + e];
    if (d >= lo && d < hi) {
      int p = atomicAdd(&cursor[d], 1);
      csr_src[p] = ei[e];
    }
  }
}

// ---- cast fp32 rows -> bf16 mirror ----
__global__ __launch_bounds__(256) void k_cast(const float* __restrict__ in, ushortT* __restrict__ outb, int total4) {
  int i = blockIdx.x * 256 + threadIdx.x;
  if (i < total4) {
    float4 v = *(const float4*)&in[i * 4];
    ushort4 o;
    o.x = f2bf(v.x); o.y = f2bf(v.y); o.z = f2bf(v.z); o.w = f2bf(v.w);
    *(ushort4*)&outb[i * 4] = o;
  }
}

// ---- mean aggregation: one wave per node, gathers bf16 rows (256B), fp32 accumulate ----
__global__ __launch_bounds__(256) void k_aggregate(const int* __restrict__ csr_off, const int* __restrict__ deg,
                                                   const int* __restrict__ csr_src, const ushortT* __restrict__ hinb,
                                                   float* __restrict__ agg, int N) {
  int wid = (blockIdx.x * 256 + threadIdx.x) >> 6;
  int lane = threadIdx.x & 63;
  if (wid >= N) return;
  int off = csr_off[wid];
  int d = deg[wid];
  int half = lane >> 5;
  int colq = (lane & 31) * 4;
  float ax = 0.f, ay = 0.f, az = 0.f, aw = 0.f;
  int j = 0;
  for (; j + 4 <= d; j += 4) {  // 4 rows in flight
    int sA = csr_src[off + j + half];
    int sB = csr_src[off + j + 2 + half];
    ushort4 vA = *(const ushort4*)&hinb[(size_t)sA * HH + colq];
    ushort4 vB = *(const ushort4*)&hinb[(size_t)sB * HH + colq];
    ax += bf2f(vA.x); ay += bf2f(vA.y); az += bf2f(vA.z); aw += bf2f(vA.w);
    ax += bf2f(vB.x); ay += bf2f(vB.y); az += bf2f(vB.z); aw += bf2f(vB.w);
  }
  for (; j + 2 <= d; j += 2) {
    int s = csr_src[off + j + half];
    ushort4 v = *(const ushort4*)&hinb[(size_t)s * HH + colq];
    ax += bf2f(v.x); ay += bf2f(v.y); az += bf2f(v.z); aw += bf2f(v.w);
  }
  if (j < d && half == 0) {
    int s = csr_src[off + j];
    ushort4 v = *(const ushort4*)&hinb[(size_t)s * HH + colq];
    ax += bf2f(v.x); ay += bf2f(v.y); az += bf2f(v.z); aw += bf2f(v.w);
  }
  ax += __shfl_down(ax, 32);
  ay += __shfl_down(ay, 32);
  az += __shfl_down(az, 32);
  aw += __shfl_down(aw, 32);
  if (half == 0) {
    float inv = d > 0 ? 1.0f / (float)d : 0.0f;
    float4 o;
    o.x = ax * inv; o.y = ay * inv; o.z = az * inv; o.w = aw * inv;
    *(float4*)&agg[(size_t)wid * HH + colq] = o;
  }
}

// ---- fused dual GEMM + bias + BN(eval) + ReLU; also emits bf16 mirror of output ----
__global__ __launch_bounds__(256) void k_gemm(const float* __restrict__ agg, const float* __restrict__ hin,
                                              const float* __restrict__ wlp, const float* __restrict__ wrp,
                                              const float* __restrict__ bias, const float* __restrict__ gma,
                                              const float* __restrict__ bta, const float* __restrict__ mea,
                                              const float* __restrict__ var, float* __restrict__ hout,
                                              ushortT* __restrict__ houtb, int N) {
  __shared__ float As[32][68];   // [k][row]
  __shared__ float Ws[32][HH];   // [k][col]
  int tid = threadIdx.x;
  int n0 = blockIdx.x * 64;
  int tc = tid & 31, tr = tid >> 5;
  int c0 = tc * 4, r0 = tr * 8;
  float acc[8][4] = {};
  for (int k0 = 0; k0 < 2 * HH; k0 += 32) {
    const float* Asrc = (k0 < HH) ? agg : hin;
    const float* Wsrc = (k0 < HH) ? wlp : wrp;
    int kk0 = k0 & (HH - 1);
    {  // stage A chunk: 64 rows x 32 k
      int row = tid >> 2;
      int kq = (tid & 3) * 8;
      int n = n0 + row;
      float4 v0, v1;
      if (n < N) {
        const float* p = Asrc + (size_t)n * HH + kk0 + kq;
        v0 = *(const float4*)p;
        v1 = *(const float4*)(p + 4);
      } else {
        v0 = make_float4(0.f, 0.f, 0.f, 0.f);
        v1 = v0;
      }
      As[kq + 0][row] = v0.x; As[kq + 1][row] = v0.y;
      As[kq + 2][row] = v0.z; As[kq + 3][row] = v0.w;
      As[kq + 4][row] = v1.x; As[kq + 5][row] = v1.y;
      As[kq + 6][row] = v1.z; As[kq + 7][row] = v1.w;
    }
    {  // stage W chunk: 32 k x 128 cols
      const float4* srcp = (const float4*)(Wsrc + (size_t)kk0 * HH);
      float4* dstp = (float4*)&Ws[0][0];
#pragma unroll
      for (int jj = 0; jj < 4; jj++) dstp[tid + jj * 256] = srcp[tid + jj * 256];
    }
    __syncthreads();
#pragma unroll
    for (int k = 0; k < 32; k++) {
      float a0[8], w0[4];
      *(float4*)&a0[0] = *(const float4*)&As[k][r0];
      *(float4*)&a0[4] = *(const float4*)&As[k][r0 + 4];
      *(float4*)&w0[0] = *(const float4*)&Ws[k][c0];
#pragma unroll
      for (int r = 0; r < 8; r++)
#pragma unroll
        for (int c = 0; c < 4; c++) acc[r][c] = fmaf(a0[r], w0[c], acc[r][c]);
    }
    __syncthreads();
  }
  float sc[4], sh[4];
#pragma unroll
  for (int c = 0; c < 4; c++) {
    float g = gma[c0 + c], vv = var[c0 + c], m = mea[c0 + c], bt = bta[c0 + c], bb = bias[c0 + c];
    float s = g * rsqrtf(vv + BN_EPS);
    sc[c] = s;
    sh[c] = (bb - m) * s + bt;
  }
#pragma unroll
  for (int r = 0; r < 8; r++) {
    int n = n0 + r0 + r;
    if (n < N) {
      float4 o;
      o.x = fmaxf(acc[r][0] * sc[0] + sh[0], 0.f);
      o.y = fmaxf(acc[r][1] * sc[1] + sh[1], 0.f);
      o.z = fmaxf(acc[r][2] * sc[2] + sh[2], 0.f);
      o.w = fmaxf(acc[r][3] * sc[3] + sh[3], 0.f);
      *(float4*)&hout[(size_t)n * HH + c0] = o;
      ushort4 ob;
      ob.x = f2bf(o.x); ob.y = f2bf(o.y); ob.z = f2bf(o.z); ob.w = f2bf(o.w);
      *(ushort4*)&houtb[(size_t)n * HH + c0] = ob;
    }
  }
}

// ---- graph pooling + concat global feats ----
__global__ __launch_bounds__(128) void k_pool(const float* __restrict__ h, const int* __restrict__ goff,
                                              const int* __restrict__ gcnt, const float* __restrict__ gfeat,
                                              float* __restrict__ pz) {
  int g = blockIdx.x;
  int t = threadIdx.x;
  int off = goff[g], cnt = gcnt[g];
  float s = 0.f;
  for (int j = 0; j < cnt; j++) s += h[(size_t)(off + j) * HH + t];
  float inv = cnt > 0 ? 1.0f / (float)cnt : 0.f;
  pz[(size_t)g * (HH + GG) + t] = s * inv;
  if (t < GG) pz[(size_t)g * (HH + GG) + HH + t] = gfeat[g * GG + t];
}

// ---- final MLP: one wave per graph ----
__global__ __launch_bounds__(64) void k_mlp(const float* __restrict__ pz, const float* __restrict__ w1,
                                            const float* __restrict__ b1, const float* __restrict__ w2,
                                            const float* __restrict__ b2, float* __restrict__ out) {
  int g = blockIdx.x;
  int t = threadIdx.x;
  const float* z = pz + (size_t)g * (HH + GG);
  float acc = b1[t];
  for (int k = 0; k < HH + GG; k++) acc = fmaf(z[k], w1[k * 64 + t], acc);
  acc = fmaxf(acc, 0.f);
  float v = acc * w2[t];
#pragma unroll
  for (int o = 32; o > 0; o >>= 1) v += __shfl_down(v, o);
  if (t == 0) out[g] = v + b2[0];
}

extern "C" void kernel_launch(void* const* d_in, const int* in_sizes, int n_in,
                              void* d_out, int out_size, void* d_ws, size_t ws_size,
                              hipStream_t stream) {
  const float* x = (const float*)d_in[0];
  const int* ei = (const int*)d_in[1];
  const int* batch = (const int*)d_in[2];
  const float* gfeat = (const float*)d_in[3];
  const float* wl = (const float*)d_in[4];
  const float* wr = (const float*)d_in[5];
  const float* bias = (const float*)d_in[6];
  const float* gma = (const float*)d_in[7];
  const float* bta = (const float*)d_in[8];
  const float* mea = (const float*)d_in[9];
  const float* var = (const float*)d_in[10];
  const float* w1 = (const float*)d_in[11];
  const float* b1 = (const float*)d_in[12];
  const float* w2 = (const float*)d_in[13];
  const float* b2 = (const float*)d_in[14];
  int N = in_sizes[0] / HH;
  int E = in_sizes[1] / 2;
  int B = in_sizes[3] / GG;
  float* out = (float*)d_out;
  (void)n_in; (void)out_size; (void)ws_size;

  char* base = (char*)d_ws;
  size_t off = 0;
  auto alloc = [&](size_t bytes) -> void* {
    void* p = base + off;
    off = (off + bytes + 255) & ~(size_t)255;
    return p;
  };
  int* deg = (int*)alloc((size_t)N * 4);
  int* csr_off = (int*)alloc((size_t)N * 4);
  int* cursor = (int*)alloc((size_t)N * 4);
  int* gcnt = (int*)alloc((size_t)B * 4);
  int* goff = (int*)alloc((size_t)B * 4);
  int* csr_src = (int*)alloc((size_t)E * 4);
  float* agg = (float*)alloc((size_t)N * HH * 4);
  float* hbA = (float*)alloc((size_t)N * HH * 4);
  float* hbB = (float*)alloc((size_t)N * HH * 4);
  ushortT* hb16 = (ushortT*)alloc((size_t)N * HH * 2);  // reused bf16 mirror (x, then h1, h2)
  float* pz = (float*)alloc((size_t)B * (HH + GG) * 4);
  int* bsumN = (int*)alloc(1024 * 4);
  int* bsumB = (int*)alloc(1024 * 4);

  hipMemsetAsync(deg, 0, (size_t)N * 4, stream);
  hipMemsetAsync(gcnt, 0, (size_t)B * 4, stream);
  k_deg<<<(E + 255) / 256, 256, 0, stream>>>(ei, deg, E);
  k_gcnt<<<(N + 255) / 256, 256, 0, stream>>>(batch, gcnt, N);

  int nbN = (N + 1023) / 1024;
  k_scan_blk<<<nbN, 1024, 0, stream>>>(deg, csr_off, bsumN, N);
  k_scan_top<<<1, 1024, 0, stream>>>(bsumN, nbN);
  k_scan_add<<<nbN, 1024, 0, stream>>>(csr_off, cursor, bsumN, N);

  int nbB = (B + 1023) / 1024;
  k_scan_blk<<<nbB, 1024, 0, stream>>>(gcnt, goff, bsumB, B);
  k_scan_top<<<1, 1024, 0, stream>>>(bsumB, nbB);
  k_scan_add<<<nbB, 1024, 0, stream>>>(goff, (int*)nullptr, bsumB, B);

  // windowed scatter: 4 dst-range passes so stores land in an L2-sized window
  const int NPASS = 4;
  int win = (N + NPASS - 1) / NPASS;
  for (int p = 0; p < NPASS; p++) {
    int lo = p * win;
    int hi = (lo + win < N) ? lo + win : N;
    k_scatter<<<(E + 255) / 256, 256, 0, stream>>>(ei, cursor, csr_src, E, lo, hi);
  }

  // bf16 mirror of x for the first gather
  k_cast<<<((N * HH / 4) + 255) / 256, 256, 0, stream>>>(x, hb16, N * HH / 4);

  int nblk = (N + 63) / 64;
  const float* hsrc[LL] = {x, hbA, hbB};
  float* hdst[LL] = {hbA, hbB, hbA};
  for (int l = 0; l < LL; l++) {
    k_aggregate<<<(N + 3) / 4, 256, 0, stream>>>(csr_off, deg, csr_src, hb16, agg, N);
    k_gemm<<<nblk, 256, 0, stream>>>(agg, hsrc[l], wl + (size_t)l * HH * HH, wr + (size_t)l * HH * HH,
                                     bias + (size_t)l * HH, gma + (size_t)l * HH, bta + (size_t)l * HH,
                                     mea + (size_t)l * HH, var + (size_t)l * HH, hdst[l], hb16, N);
  }
  k_pool<<<B, 128, 0, stream>>>(hbA, goff, gcnt, gfeat, pz);
  k_mlp<<<B, 64, 0, stream>>>(pz, w1, b1, w2, b2, out);
}

// Round 5
// 306.216 us; speedup vs baseline: 3.2103x; 1.4253x over previous
//
#include <hip/hip_runtime.h>

#define HH 128
#define GG 32
#define LL 3
#define BN_EPS 1e-5f

typedef unsigned short ushortT;
typedef unsigned int uintT;
typedef __attribute__((ext_vector_type(8))) short bf16x8;
typedef __attribute__((ext_vector_type(4))) float f32x4;

__device__ inline ushortT f2bf(float f) {
  uintT u = __float_as_uint(f);
  u += 0x7fff + ((u >> 16) & 1);  // RNE
  return (ushortT)(u >> 16);
}
__device__ inline float bf2f(ushortT u) { return __uint_as_float(((uintT)u) << 16); }

// ---- CSR build ----
__global__ __launch_bounds__(256) void k_deg(const int* __restrict__ ei, int* __restrict__ deg, int E) {
  int e = blockIdx.x * 256 + threadIdx.x;
  if (e < E) atomicAdd(&deg[ei[E + e]], 1);
}

__global__ __launch_bounds__(256) void k_gcnt(const int* __restrict__ batch, int* __restrict__ gcnt, int N) {
  int n = blockIdx.x * 256 + threadIdx.x;
  if (n < N) atomicAdd(&gcnt[batch[n]], 1);
}

// ---- parallel 3-phase exclusive scan ----
__global__ __launch_bounds__(1024) void k_scan_blk(const int* __restrict__ in, int* __restrict__ out,
                                                   int* __restrict__ bsum, int n) {
  __shared__ int sd[1024];
  int tid = threadIdx.x;
  int i = blockIdx.x * 1024 + tid;
  int v = (i < n) ? in[i] : 0;
  sd[tid] = v;
  __syncthreads();
  for (int off = 1; off < 1024; off <<= 1) {
    int t = (tid >= off) ? sd[tid - off] : 0;
    __syncthreads();
    sd[tid] += t;
    __syncthreads();
  }
  if (i < n) out[i] = sd[tid] - v;
  if (tid == 1023) bsum[blockIdx.x] = sd[1023];
}

__global__ __launch_bounds__(1024) void k_scan_top(int* __restrict__ bsum, int nb) {
  __shared__ int sd[1024];
  int tid = threadIdx.x;
  int v = (tid < nb) ? bsum[tid] : 0;
  sd[tid] = v;
  __syncthreads();
  for (int off = 1; off < 1024; off <<= 1) {
    int t = (tid >= off) ? sd[tid - off] : 0;
    __syncthreads();
    sd[tid] += t;
    __syncthreads();
  }
  if (tid < nb) bsum[tid] = sd[tid] - v;
}

__global__ __launch_bounds__(1024) void k_scan_add(int* __restrict__ out0, int* __restrict__ out1,
                                                   const int* __restrict__ bsum, int n) {
  int i = blockIdx.x * 1024 + threadIdx.x;
  if (i < n) {
    int v = out0[i] + bsum[blockIdx.x];
    out0[i] = v;
    if (out1) out1[i] = v;
  }
}

// ---- windowed scatter ----
__global__ __launch_bounds__(256) void k_scatter(const int* __restrict__ ei, int* __restrict__ cursor,
                                                 int* __restrict__ csr_src, int E, int lo, int hi) {
  int e = blockIdx.x * 256 + threadIdx.x;
  if (e < E) {
    int d = ei[E + e];
    if (d >= lo && d < hi) {
      int p = atomicAdd(&cursor[d], 1);
      csr_src[p] = ei[e];
    }
  }
}

// ---- cast fp32 rows -> bf16 mirror ----
__global__ __launch_bounds__(256) void k_cast(const float* __restrict__ in, ushortT* __restrict__ outb, int total4) {
  int i = blockIdx.x * 256 + threadIdx.x;
  if (i < total4) {
    float4 v = *(const float4*)&in[i * 4];
    ushort4 o;
    o.x = f2bf(v.x); o.y = f2bf(v.y); o.z = f2bf(v.z); o.w = f2bf(v.w);
    *(ushort4*)&outb[i * 4] = o;
  }
}

// ---- pack weights for MFMA B-fragment reads ----
// wpack[layer][kf(8)][n(128)][q(4)][j(8)] = W[kf*32+q*8+j][n], W = [wl;wr] (K=256)
__global__ __launch_bounds__(256) void k_prepw(const float* __restrict__ wl, const float* __restrict__ wr,
                                               ushortT* __restrict__ wpack) {
  int idx = blockIdx.x * 256 + threadIdx.x;
  if (idx >= LL * 8 * 128 * 4) return;
  int q = idx & 3;
  int n = (idx >> 2) & 127;
  int kf = (idx >> 9) & 7;
  int layer = idx >> 12;
  ushortT tmp[8];
#pragma unroll
  for (int j = 0; j < 8; j++) {
    int k = kf * 32 + q * 8 + j;
    float w = (k < HH) ? wl[(size_t)layer * HH * HH + k * HH + n]
                       : wr[(size_t)layer * HH * HH + (k - HH) * HH + n];
    tmp[j] = f2bf(w);
  }
  ushort4 a = {tmp[0], tmp[1], tmp[2], tmp[3]};
  ushort4 b = {tmp[4], tmp[5], tmp[6], tmp[7]};
  *(ushort4*)&wpack[(size_t)idx * 8] = a;
  *(ushort4*)&wpack[(size_t)idx * 8 + 4] = b;
}

// ---- mean aggregation: one wave per node, bf16 gather, fp32 accumulate, bf16 out ----
__global__ __launch_bounds__(256) void k_aggregate(const int* __restrict__ csr_off, const int* __restrict__ deg,
                                                   const int* __restrict__ csr_src, const ushortT* __restrict__ hinb,
                                                   ushortT* __restrict__ aggb, int N) {
  int wid = (blockIdx.x * 256 + threadIdx.x) >> 6;
  int lane = threadIdx.x & 63;
  if (wid >= N) return;
  int off = csr_off[wid];
  int d = deg[wid];
  int half = lane >> 5;
  int colq = (lane & 31) * 4;
  float ax = 0.f, ay = 0.f, az = 0.f, aw = 0.f;
  int j = 0;
  for (; j + 4 <= d; j += 4) {
    int sA = csr_src[off + j + half];
    int sB = csr_src[off + j + 2 + half];
    ushort4 vA = *(const ushort4*)&hinb[(size_t)sA * HH + colq];
    ushort4 vB = *(const ushort4*)&hinb[(size_t)sB * HH + colq];
    ax += bf2f(vA.x); ay += bf2f(vA.y); az += bf2f(vA.z); aw += bf2f(vA.w);
    ax += bf2f(vB.x); ay += bf2f(vB.y); az += bf2f(vB.z); aw += bf2f(vB.w);
  }
  for (; j + 2 <= d; j += 2) {
    int s = csr_src[off + j + half];
    ushort4 v = *(const ushort4*)&hinb[(size_t)s * HH + colq];
    ax += bf2f(v.x); ay += bf2f(v.y); az += bf2f(v.z); aw += bf2f(v.w);
  }
  if (j < d && half == 0) {
    int s = csr_src[off + j];
    ushort4 v = *(const ushort4*)&hinb[(size_t)s * HH + colq];
    ax += bf2f(v.x); ay += bf2f(v.y); az += bf2f(v.z); aw += bf2f(v.w);
  }
  ax += __shfl_down(ax, 32);
  ay += __shfl_down(ay, 32);
  az += __shfl_down(az, 32);
  aw += __shfl_down(aw, 32);
  if (half == 0) {
    float inv = d > 0 ? 1.0f / (float)d : 0.0f;
    ushort4 o;
    o.x = f2bf(ax * inv); o.y = f2bf(ay * inv); o.z = f2bf(az * inv); o.w = f2bf(aw * inv);
    *(ushort4*)&aggb[(size_t)wid * HH + colq] = o;
  }
}

// ---- MFMA dual GEMM + bias + BN + ReLU -> bf16 h ----
// block: 64 rows x 128 cols, 4 waves; wave w owns cols [w*32, w*32+32)
// A = [aggb | hinb] (K=256) staged in LDS (XOR-swizzled); B preloaded to registers from wpack
__global__ __launch_bounds__(256) void k_gemm(const ushortT* __restrict__ aggb, const ushortT* __restrict__ hinb,
                                              const ushortT* __restrict__ wpack, const float* __restrict__ bias,
                                              const float* __restrict__ gma, const float* __restrict__ bta,
                                              const float* __restrict__ mea, const float* __restrict__ var,
                                              ushortT* __restrict__ houtb, int N) {
  __shared__ char Asm[64 * 512];  // 64 rows x 256 bf16 (512B/row), XOR-swizzled
  int tid = threadIdx.x;
  int l = tid & 63;
  int w = tid >> 6;
  int n0 = blockIdx.x * 64;
  int q = l >> 4;
  int ln = l & 15;

  // preload B fragments: 8 k-frags x 2 n-frags per wave
  bf16x8 bfr[8][2];
#pragma unroll
  for (int kf = 0; kf < 8; kf++)
#pragma unroll
    for (int nf = 0; nf < 2; nf++) {
      size_t off = (((size_t)kf * 128 + (w * 32 + nf * 16 + ln)) * 4 + q) * 8;
      bfr[kf][nf] = *(const bf16x8*)(wpack + off);
    }

  // stage A: 64 rows x 32 chunks of 16B; first 16 chunks = aggb row, last 16 = hinb row
#pragma unroll
  for (int r2 = 0; r2 < 8; r2++) {
    int c = r2 * 256 + tid;
    int row = c >> 5;
    int col16 = c & 31;
    int rg = n0 + row;
    rg = rg < N ? rg : N - 1;  // clamp: OOB rows read valid data, stores are masked later
    const ushortT* src = (col16 < 16) ? (aggb + (size_t)rg * HH + col16 * 8)
                                      : (hinb + (size_t)rg * HH + (col16 - 16) * 8);
    float4 v = *(const float4*)src;
    int waddr = row * 512 + ((col16 * 16) ^ ((row & 7) << 4));
    *(float4*)(Asm + waddr) = v;
  }
  __syncthreads();

  f32x4 acc[4][2] = {};
#pragma unroll
  for (int kf = 0; kf < 8; kf++) {
#pragma unroll
    for (int rt = 0; rt < 4; rt++) {
      int row = rt * 16 + ln;
      int raddr = row * 512 + ((kf * 64 + q * 16) ^ ((row & 7) << 4));
      bf16x8 a = *(const bf16x8*)(Asm + raddr);
      acc[rt][0] = __builtin_amdgcn_mfma_f32_16x16x32_bf16(a, bfr[kf][0], acc[rt][0], 0, 0, 0);
      acc[rt][1] = __builtin_amdgcn_mfma_f32_16x16x32_bf16(a, bfr[kf][1], acc[rt][1], 0, 0, 0);
    }
  }

  // epilogue: per-col scale/shift (bias+BN folded), ReLU, bf16 store
  float sc[2], sh[2];
  int colg[2];
#pragma unroll
  for (int nf = 0; nf < 2; nf++) {
    int c = w * 32 + nf * 16 + ln;
    colg[nf] = c;
    float g = gma[c], vv = var[c], m = mea[c], bt = bta[c], bb = bias[c];
    float s = g * rsqrtf(vv + BN_EPS);
    sc[nf] = s;
    sh[nf] = (bb - m) * s + bt;
  }
#pragma unroll
  for (int rt = 0; rt < 4; rt++)
#pragma unroll
    for (int j = 0; j < 4; j++) {
      int row = n0 + rt * 16 + q * 4 + j;
      if (row < N) {
#pragma unroll
        for (int nf = 0; nf < 2; nf++) {
          float v = fmaxf(acc[rt][nf][j] * sc[nf] + sh[nf], 0.f);
          houtb[(size_t)row * HH + colg[nf]] = f2bf(v);
        }
      }
    }
}

// ---- graph pooling (bf16 h) + concat global feats ----
__global__ __launch_bounds__(128) void k_pool(const ushortT* __restrict__ hb, const int* __restrict__ goff,
                                              const int* __restrict__ gcnt, const float* __restrict__ gfeat,
                                              float* __restrict__ pz) {
  int g = blockIdx.x;
  int t = threadIdx.x;
  int off = goff[g], cnt = gcnt[g];
  float s = 0.f;
  for (int j = 0; j < cnt; j++) s += bf2f(hb[(size_t)(off + j) * HH + t]);
  float inv = cnt > 0 ? 1.0f / (float)cnt : 0.f;
  pz[(size_t)g * (HH + GG) + t] = s * inv;
  if (t < GG) pz[(size_t)g * (HH + GG) + HH + t] = gfeat[g * GG + t];
}

// ---- final MLP: one wave per graph ----
__global__ __launch_bounds__(64) void k_mlp(const float* __restrict__ pz, const float* __restrict__ w1,
                                            const float* __restrict__ b1, const float* __restrict__ w2,
                                            const float* __restrict__ b2, float* __restrict__ out) {
  int g = blockIdx.x;
  int t = threadIdx.x;
  const float* z = pz + (size_t)g * (HH + GG);
  float acc = b1[t];
  for (int k = 0; k < HH + GG; k++) acc = fmaf(z[k], w1[k * 64 + t], acc);
  acc = fmaxf(acc, 0.f);
  float v = acc * w2[t];
#pragma unroll
  for (int o = 32; o > 0; o >>= 1) v += __shfl_down(v, o);
  if (t == 0) out[g] = v + b2[0];
}

extern "C" void kernel_launch(void* const* d_in, const int* in_sizes, int n_in,
                              void* d_out, int out_size, void* d_ws, size_t ws_size,
                              hipStream_t stream) {
  const float* x = (const float*)d_in[0];
  const int* ei = (const int*)d_in[1];
  const int* batch = (const int*)d_in[2];
  const float* gfeat = (const float*)d_in[3];
  const float* wl = (const float*)d_in[4];
  const float* wr = (const float*)d_in[5];
  const float* bias = (const float*)d_in[6];
  const float* gma = (const float*)d_in[7];
  const float* bta = (const float*)d_in[8];
  const float* mea = (const float*)d_in[9];
  const float* var = (const float*)d_in[10];
  const float* w1 = (const float*)d_in[11];
  const float* b1 = (const float*)d_in[12];
  const float* w2 = (const float*)d_in[13];
  const float* b2 = (const float*)d_in[14];
  int N = in_sizes[0] / HH;
  int E = in_sizes[1] / 2;
  int B = in_sizes[3] / GG;
  float* out = (float*)d_out;
  (void)n_in; (void)out_size; (void)ws_size;

  char* base = (char*)d_ws;
  size_t off = 0;
  auto alloc = [&](size_t bytes) -> void* {
    void* p = base + off;
    off = (off + bytes + 255) & ~(size_t)255;
    return p;
  };
  int* deg = (int*)alloc((size_t)N * 4);
  int* csr_off = (int*)alloc((size_t)N * 4);
  int* cursor = (int*)alloc((size_t)N * 4);
  int* gcnt = (int*)alloc((size_t)B * 4);
  int* goff = (int*)alloc((size_t)B * 4);
  int* csr_src = (int*)alloc((size_t)E * 4);
  ushortT* xb = (ushortT*)alloc((size_t)N * HH * 2);
  ushortT* h1b = (ushortT*)alloc((size_t)N * HH * 2);
  ushortT* h2b = (ushortT*)alloc((size_t)N * HH * 2);
  ushortT* aggb = (ushortT*)alloc((size_t)N * HH * 2);
  ushortT* wpack = (ushortT*)alloc((size_t)LL * 8 * 128 * 4 * 8 * 2);
  float* pz = (float*)alloc((size_t)B * (HH + GG) * 4);
  int* bsumN = (int*)alloc(1024 * 4);
  int* bsumB = (int*)alloc(1024 * 4);

  hipMemsetAsync(deg, 0, (size_t)N * 4, stream);
  hipMemsetAsync(gcnt, 0, (size_t)B * 4, stream);
  k_deg<<<(E + 255) / 256, 256, 0, stream>>>(ei, deg, E);
  k_gcnt<<<(N + 255) / 256, 256, 0, stream>>>(batch, gcnt, N);

  int nbN = (N + 1023) / 1024;
  k_scan_blk<<<nbN, 1024, 0, stream>>>(deg, csr_off, bsumN, N);
  k_scan_top<<<1, 1024, 0, stream>>>(bsumN, nbN);
  k_scan_add<<<nbN, 1024, 0, stream>>>(csr_off, cursor, bsumN, N);

  int nbB = (B + 1023) / 1024;
  k_scan_blk<<<nbB, 1024, 0, stream>>>(gcnt, goff, bsumB, B);
  k_scan_top<<<1, 1024, 0, stream>>>(bsumB, nbB);
  k_scan_add<<<nbB, 1024, 0, stream>>>(goff, (int*)nullptr, bsumB, B);

  const int NPASS = 4;
  int win = (N + NPASS - 1) / NPASS;
  for (int p = 0; p < NPASS; p++) {
    int lo = p * win;
    int hi = (lo + win < N) ? lo + win : N;
    k_scatter<<<(E + 255) / 256, 256, 0, stream>>>(ei, cursor, csr_src, E, lo, hi);
  }

  k_cast<<<((N * HH / 4) + 255) / 256, 256, 0, stream>>>(x, xb, N * HH / 4);
  k_prepw<<<(LL * 8 * 128 * 4 + 255) / 256, 256, 0, stream>>>(wl, wr, wpack);

  int nblk = (N + 63) / 64;
  const ushortT* hsrc[LL] = {xb, h1b, h2b};
  ushortT* hdst[LL] = {h1b, h2b, h1b};
  for (int lyr = 0; lyr < LL; lyr++) {
    k_aggregate<<<(N + 3) / 4, 256, 0, stream>>>(csr_off, deg, csr_src, hsrc[lyr], aggb, N);
    k_gemm<<<nblk, 256, 0, stream>>>(aggb, hsrc[lyr], wpack + (size_t)lyr * 32768,
                                     bias + (size_t)lyr * HH, gma + (size_t)lyr * HH, bta + (size_t)lyr * HH,
                                     mea + (size_t)lyr * HH, var + (size_t)lyr * HH, hdst[lyr], N);
  }
  k_pool<<<B, 128, 0, stream>>>(h1b, goff, gcnt, gfeat, pz);
  k_mlp<<<B, 64, 0, stream>>>(pz, w1, b1, w2, b2, out);
}